// Round 4
// baseline (13828.000 us; speedup 1.0000x reference)
//
#include <hip/hip_runtime.h>
#include <math.h>

// Persistent-kernel LSTM: H=2048, SEQ=4096, fp32 (no fp32 MFMA -> vector ALU).
// 256 WGs x 512 thr, 1 WG/CU. Wave w of WG g owns hidden unit k=g*8+w; each
// lane holds 4 gate-rows x 32 cols of W_hh (128 floats).
//
// Cross-step exchange v7: STAMPED MAILBOX BROADCAST.
//   Each h value is published as ONE 8-byte atomic word {hi: stamp=t+1,
//   lo: f32 bits} replicated into NINBOX (8) inbox copies (lanes 0..7 of the
//   producing wave issue one scattered store each). Consumer WG c polls ONLY
//   inbox[c & 7]: each thread re-loads just its own 4 stamped words until
//   stamps match t. The poll IS the data load -> the flag store trip, the
//   flag-visibility trip, the drain barrier (B3) and the post-detect data
//   read of v5 are all gone. One barrier per step.
//   Why this dodges the v3/v4 regressions:
//    - full per-step machine resync (every WG gates on ALL 2048 stamps every
//      step) -> no drift compounding (v3's failure);
//    - per-inbox-line traffic: 8 writes + ~32 coalesced read-reqs/sweep --
//      LIGHTER than v2's proven flag lines (256 reqs/line/sweep);
//    - monotone stamps -> no sentinel resets, no epoch races.
//   Slot safety (2-slot parity): producer overwrites slot t&1 at step t+2
//   only after observing stamps t+2, which requires every WG to have pushed
//   h_{t+1}, which happens only after that WG finished polling slot t&1.
// Compute path identical to v5 (fast gates, 16-shuffle reduction) to keep
// this round single-variable.
// d_ws: ninbox*2*2048*8B (8 -> 256 KB), host falls back to fewer copies if
// ws_size is small.

#define HDIM 2048
#define SEQ 4096
#define NWG 256
#define TPB 512
#define GUARD_MAX 65536   // bounded retries: protocol failure -> loud wrong answer, no hang

typedef unsigned long long u64;

__device__ __forceinline__ float sigmoidf_(float x) {
  return __builtin_amdgcn_rcpf(1.0f + __expf(-x));
}
__device__ __forceinline__ float tanh_(float x) {
  float e = __expf(-2.0f * fabsf(x));
  float r = (1.0f - e) * __builtin_amdgcn_rcpf(1.0f + e);
  return copysignf(r, x);
}

// zero everything: slot1 {stamp 0, h=0.0} is exactly what t=0 wants (h_{-1}=0);
// slot0 zeros mismatch every wanted stamp (>=1) -> retried until written.
__global__ void lstm_init(u64* inbox, int words) {
  const int i = blockIdx.x * 256 + threadIdx.x;
  if (i < words) inbox[i] = 0ull;
}

__global__ __launch_bounds__(TPB, 2) void lstm_persist(
    const float* __restrict__ x, const float* __restrict__ w_ih,
    const float* __restrict__ w_hh, const float* __restrict__ b_ih,
    const float* __restrict__ b_hh, const float* __restrict__ w_out,
    const float* __restrict__ b_out, float* __restrict__ out,
    u64* __restrict__ inbox, int ninbox)
{
  const int wg   = blockIdx.x;
  const int tid  = threadIdx.x;
  const int wave = tid >> 6;
  const int lane = tid & 63;
  const int k    = wg * 8 + wave;        // this wave's hidden unit
  const int grp  = wg & (ninbox - 1);    // which inbox copy we read

  __shared__ float xs[SEQ];        // 16 KB
  __shared__ float hs[2][HDIM];    // 16 KB, double-buffered by parity
  __shared__ float wys[2][8];      // per-wave y partials, double-buffered

  // ---- one-time: weights into registers ----
  // rows g=0..3 (gates i,f,g,o of unit k): row = k + g*HDIM
  // cols per lane: {256*j + 4*lane + q}, j=0..7, q=0..3  -> 32 float4
  float4 W[32];
  float wx[4], bb[4];
  #pragma unroll
  for (int g = 0; g < 4; ++g) {
    const int row = k + g * HDIM;
    const float* rp = w_hh + (size_t)row * HDIM + lane * 4;
    #pragma unroll
    for (int j = 0; j < 8; ++j)
      W[g * 8 + j] = *(const float4*)(rp + j * 256);
    wx[g] = w_ih[row];
    bb[g] = b_ih[row] + b_hh[row];
  }
  float wo[4];
  #pragma unroll
  for (int q = 0; q < 4; ++q) wo[q] = w_out[tid + TPB * q];
  const float bout = b_out[0];

  for (int i = tid; i < SEQ; i += TPB) xs[i] = x[i];

  float cc = 0.f, hh = 0.f;
  float hv[4];
  __syncthreads();   // xs ready (also covers init-kernel completion via stream order)

  for (int t = 0; t < SEQ; ++t) {
    const int par = t & 1;

    // ---- poll+gather h_{t-1}: slot (t-1)&1 == (t+1)&1, wanted stamp == t ----
    {
      const u64* src = inbox + (size_t)grp * (2 * HDIM) +
                       (size_t)((t + 1) & 1) * HDIM;
      const unsigned wanted = (unsigned)t;
      u64 v[4];
      #pragma unroll
      for (int q = 0; q < 4; ++q)
        v[q] = __hip_atomic_load(&src[tid + TPB * q], __ATOMIC_RELAXED,
                                 __HIP_MEMORY_SCOPE_AGENT);
      for (int guard = 0;;) {
        const int miss = ((unsigned)(v[0] >> 32) != wanted) |
                         ((unsigned)(v[1] >> 32) != wanted) |
                         ((unsigned)(v[2] >> 32) != wanted) |
                         ((unsigned)(v[3] >> 32) != wanted);
        if (!__any(miss) || ++guard > GUARD_MAX) break;
        #pragma unroll
        for (int q = 0; q < 4; ++q)      // re-load only still-missing words
          if ((unsigned)(v[q] >> 32) != wanted)
            v[q] = __hip_atomic_load(&src[tid + TPB * q], __ATOMIC_RELAXED,
                                     __HIP_MEMORY_SCOPE_AGENT);
      }
      #pragma unroll
      for (int q = 0; q < 4; ++q) {
        hv[q] = __uint_as_float((unsigned)v[q]);
        hs[par][tid + TPB * q] = hv[q];
      }
    }
    __syncthreads();  // B: hs[par] ready (single barrier per step)

    // ---- off-path: drain y_{t-2} (wys[par^1] written at step t-1) ----
    if (t >= 2 && wg == 0 && tid == 0)
      out[t - 2] = wys[par ^ 1][0] + wys[par ^ 1][1] + wys[par ^ 1][2] +
                   wys[par ^ 1][3] + wys[par ^ 1][4] + wys[par ^ 1][5] +
                   wys[par ^ 1][6] + wys[par ^ 1][7] + bout;

    // ---- z = W_hh @ h (per-lane partials over 32 columns) ----
    float acc[4] = {0.f, 0.f, 0.f, 0.f};
    #pragma unroll
    for (int j = 0; j < 8; ++j) {
      const float4 h4 = *(const float4*)&hs[par][j * 256 + lane * 4];
      #pragma unroll
      for (int g = 0; g < 4; ++g) {
        const float4 w = W[g * 8 + j];
        acc[g] = fmaf(w.x, h4.x, acc[g]);
        acc[g] = fmaf(w.y, h4.y, acc[g]);
        acc[g] = fmaf(w.z, h4.z, acc[g]);
        acc[g] = fmaf(w.w, h4.w, acc[g]);
      }
    }
    // ---- 16-shuffle reduction: fold xor32, pack gate pairs into halves,
    // 5 within-half stages, 1 cross-half gather (verified prior rounds) ----
    const float a0 = acc[0] + __shfl_xor(acc[0], 32, 64);
    const float a1 = acc[1] + __shfl_xor(acc[1], 32, 64);
    const float a2 = acc[2] + __shfl_xor(acc[2], 32, 64);
    const float a3 = acc[3] + __shfl_xor(acc[3], 32, 64);
    const bool lohalf = (lane < 32);
    float s01 = lohalf ? a0 : a1;
    float s23 = lohalf ? a2 : a3;
    #pragma unroll
    for (int off = 16; off >= 1; off >>= 1) {
      s01 += __shfl_xor(s01, off, 64);
      s23 += __shfl_xor(s23, off, 64);
    }
    const float o01 = __shfl_xor(s01, 32, 64);
    const float o23 = __shfl_xor(s23, 32, 64);
    float z[4];
    z[0] = lohalf ? s01 : o01;
    z[1] = lohalf ? o01 : s01;
    z[2] = lohalf ? s23 : o23;
    z[3] = lohalf ? o23 : s23;

    const float xt = xs[t];
    #pragma unroll
    for (int g = 0; g < 4; ++g) z[g] = fmaf(xt, wx[g], z[g] + bb[g]);

    // ---- gates (lane-redundant, identical values) ----
    const float gi = sigmoidf_(z[0]), gf = sigmoidf_(z[1]);
    const float gg = tanh_(z[2]), go = sigmoidf_(z[3]);
    cc = gf * cc + gi * gg;
    hh = go * tanh_(cc);

    // ---- publish h_t: ONE 8B stamped store per inbox copy (lanes 0..ninbox-1;
    // hh is lane-redundant so each lane pushes the same packed word) ----
    if (lane < ninbox) {
      const u64 pack = ((u64)(unsigned)(t + 1) << 32) |
                       (u64)__float_as_uint(hh);
      __hip_atomic_store(&inbox[(size_t)lane * (2 * HDIM) +
                                (size_t)(t & 1) * HDIM + k],
                         pack, __ATOMIC_RELAXED, __HIP_MEMORY_SCOPE_AGENT);
    }

    // ---- off-path: y_{t-1} partial from hv (h_{t-1}); keeps ~150cy between
    // our push and the next iteration's first poll check ----
    float sy = 0.f;
    #pragma unroll
    for (int q = 0; q < 4; ++q) sy = fmaf(wo[q], hv[q], sy);
    #pragma unroll
    for (int off = 32; off >= 1; off >>= 1) sy += __shfl_xor(sy, off, 64);
    if (lane == 0) wys[par][wave] = sy;
  }

  // ---- epilogue ----
  __syncthreads();  // wys[1] (y partial for h_{SEQ-2}) complete
  if (wg == 0 && tid == 0)
    out[SEQ - 2] = wys[1][0] + wys[1][1] + wys[1][2] + wys[1][3] + wys[1][4] +
                   wys[1][5] + wys[1][6] + wys[1][7] + bout;

  // final h, c
  if (lane == 0) {
    out[SEQ + k] = hh;
    out[SEQ + HDIM + k] = cc;
  }

  if (wg == 0) {
    // y_{SEQ-1} = w_out . h_{SEQ-1}: poll inbox copy 0, slot (SEQ-1)&1 == 1,
    // wanted stamp == SEQ
    const u64* src = inbox + (size_t)1 * HDIM;
    u64 v[4];
    #pragma unroll
    for (int q = 0; q < 4; ++q)
      v[q] = __hip_atomic_load(&src[tid + TPB * q], __ATOMIC_RELAXED,
                               __HIP_MEMORY_SCOPE_AGENT);
    for (int guard = 0;;) {
      const int miss = ((unsigned)(v[0] >> 32) != (unsigned)SEQ) |
                       ((unsigned)(v[1] >> 32) != (unsigned)SEQ) |
                       ((unsigned)(v[2] >> 32) != (unsigned)SEQ) |
                       ((unsigned)(v[3] >> 32) != (unsigned)SEQ);
      if (!__any(miss) || ++guard > GUARD_MAX) break;
      #pragma unroll
      for (int q = 0; q < 4; ++q)
        if ((unsigned)(v[q] >> 32) != (unsigned)SEQ)
          v[q] = __hip_atomic_load(&src[tid + TPB * q], __ATOMIC_RELAXED,
                                   __HIP_MEMORY_SCOPE_AGENT);
    }
    float sy = 0.f;
    #pragma unroll
    for (int q = 0; q < 4; ++q)
      sy = fmaf(wo[q], __uint_as_float((unsigned)v[q]), sy);
    #pragma unroll
    for (int off = 32; off >= 1; off >>= 1) sy += __shfl_xor(sy, off, 64);
    if (lane == 0) wys[0][wave] = sy;
    __syncthreads();
    if (tid == 0)
      out[SEQ - 1] = wys[0][0] + wys[0][1] + wys[0][2] + wys[0][3] +
                     wys[0][4] + wys[0][5] + wys[0][6] + wys[0][7] + bout;
  }
}

extern "C" void kernel_launch(void* const* d_in, const int* in_sizes, int n_in,
                              void* d_out, int out_size, void* d_ws, size_t ws_size,
                              hipStream_t stream) {
  const float* x     = (const float*)d_in[0];
  const float* w_ih  = (const float*)d_in[1];
  const float* w_hh  = (const float*)d_in[2];
  const float* b_ih  = (const float*)d_in[3];
  const float* b_hh  = (const float*)d_in[4];
  const float* w_out = (const float*)d_in[5];
  const float* b_out = (const float*)d_in[6];
  float* out = (float*)d_out;

  // ws layout: inbox[ninbox][2][2048] u64. 8 copies = 256 KB; degrade to
  // fewer copies (4/2/1) if the workspace is smaller (1 copy = 32 KB, the
  // footprint proven available in earlier rounds).
  int ninbox = 8;
  while (ninbox > 1 &&
         (size_t)ninbox * 2 * HDIM * sizeof(u64) > ws_size)
    ninbox >>= 1;
  u64* inbox = (u64*)d_ws;

  const int words = ninbox * 2 * HDIM;
  lstm_init<<<(words + 255) / 256, 256, 0, stream>>>(inbox, words);
  lstm_persist<<<NWG, TPB, 0, stream>>>(x, w_ih, w_hh, b_ih, b_hh, w_out,
                                        b_out, out, inbox, ninbox);
}

// Round 6
// 8392.901 us; speedup vs baseline: 1.6476x; 1.6476x over previous
//
#include <hip/hip_runtime.h>
#include <math.h>

// Persistent-kernel LSTM: H=2048, SEQ=4096, fp32 (no fp32 MFMA -> vector ALU).
// 256 WGs x 512 thr, 1 WG/CU. Wave w of WG g owns hidden unit k=g*8+w; each
// lane holds 4 gate-rows x 32 cols of W_hh (128 floats).
//
// Cross-step exchange v8 (resubmit; round-5 bench was an infra failure with
// no counters): PACKED FULL-LINE STAMPED PUBLISH.
//   inbox[2][2048] u64 (32 KB, LLC-resident). Word u = {stamp:hi32, h:f32}.
//   A WG's 8 units are contiguous -> its 8 stamped words are EXACTLY one
//   64B line. Publish: waves drop {t+1, h} into LDS; cheap barrier; wave 0
//   lanes 0..7 emit ONE coalesced 64B full-line store. Consumers poll their
//   own 4 stamped words (wave-coalesced) until stamp==t: the poll IS the
//   data load. No drain barrier, no flag store, no flag-visibility trip,
//   no post-detect read.
//   Why v8 after three data-poll regressions: failure table isolates WRITE
//   SHAPE as the uncontrolled variable -- v3/v4/v7 all published polled
//   lines with scattered PARTIAL-line stores (v7: WRITE_SIZE 2.1 GB of
//   sector write-back). v8's publishes are clean full-line writes (32 KB/
//   step machine-wide); read rate per line (256 req/sweep) matches v2's
//   proven flag lines. If v8 lands >=11 ms, data-polling is closed.
//   Slot-parity overwrite safety (2 slots, monotone stamps): WG g's poll
//   pass at step s+2 (stamps s+2 everywhere) proves every WG finished its
//   step-(s+1) poll of slot s&1, so g's step-(s+2) publish into slot s&1
//   cannot race a reader; exact-equality stamp compare makes early peeks
//   retry. hpk single-buffering: wave0's publish-read at step t precedes
//   B1(t+1) which precedes any hpk write at t+1.
// Hardening vs round-4 source: GUARD_MAX 65536 -> 16384 so even total
// protocol failure exits in seconds (loud wrong answer, never a wedge).
// Compute path identical to v5 (fast gates, 16-shuffle reduction).
// d_ws: 32 KB.

#define HDIM 2048
#define SEQ 4096
#define NWG 256
#define TPB 512
#define GUARD_MAX 16384   // bounded retries: protocol failure -> loud wrong answer, no hang

typedef unsigned long long u64;

__device__ __forceinline__ float sigmoidf_(float x) {
  return __builtin_amdgcn_rcpf(1.0f + __expf(-x));
}
__device__ __forceinline__ float tanh_(float x) {
  float e = __expf(-2.0f * fabsf(x));
  float r = (1.0f - e) * __builtin_amdgcn_rcpf(1.0f + e);
  return copysignf(r, x);
}

// zero both slots: slot1 {stamp 0, h=0} is exactly what t=0 wants (h_{-1}=0);
// slot0 zeros mismatch wanted stamps (>=1) -> retried until written.
__global__ void lstm_init(u64* inbox) {
  const int i = blockIdx.x * 256 + threadIdx.x;   // 16 x 256 = 4096 words
  inbox[i] = 0ull;
}

__global__ __launch_bounds__(TPB, 2) void lstm_persist(
    const float* __restrict__ x, const float* __restrict__ w_ih,
    const float* __restrict__ w_hh, const float* __restrict__ b_ih,
    const float* __restrict__ b_hh, const float* __restrict__ w_out,
    const float* __restrict__ b_out, float* __restrict__ out,
    u64* __restrict__ inbox)
{
  const int wg   = blockIdx.x;
  const int tid  = threadIdx.x;
  const int wave = tid >> 6;
  const int lane = tid & 63;
  const int k    = wg * 8 + wave;   // this wave's hidden unit

  __shared__ float xs[SEQ];        // 16 KB
  __shared__ float hs[2][HDIM];    // 16 KB, double-buffered by parity
  __shared__ float wys[2][8];      // per-wave y partials, double-buffered
  __shared__ u64   hpk[8];         // packed {stamp,h} per wave (see header)

  // ---- one-time: weights into registers ----
  // rows g=0..3 (gates i,f,g,o of unit k): row = k + g*HDIM
  // cols per lane: {256*j + 4*lane + q}, j=0..7, q=0..3  -> 32 float4
  float4 W[32];
  float wx[4], bb[4];
  #pragma unroll
  for (int g = 0; g < 4; ++g) {
    const int row = k + g * HDIM;
    const float* rp = w_hh + (size_t)row * HDIM + lane * 4;
    #pragma unroll
    for (int j = 0; j < 8; ++j)
      W[g * 8 + j] = *(const float4*)(rp + j * 256);
    wx[g] = w_ih[row];
    bb[g] = b_ih[row] + b_hh[row];
  }
  float wo[4];
  #pragma unroll
  for (int q = 0; q < 4; ++q) wo[q] = w_out[tid + TPB * q];
  const float bout = b_out[0];

  for (int i = tid; i < SEQ; i += TPB) xs[i] = x[i];

  float cc = 0.f, hh = 0.f;
  float hv[4];
  __syncthreads();   // xs ready

  for (int t = 0; t < SEQ; ++t) {
    const int par = t & 1;

    // ---- poll+gather h_{t-1}: slot (t+1)&1, wanted stamp == t ----
    // Every thread polls its own 4 words (wave-coalesced: 8 lines/load op).
    {
      const u64* src = inbox + (size_t)((t + 1) & 1) * HDIM;
      const unsigned wanted = (unsigned)t;
      u64 v[4];
      #pragma unroll
      for (int q = 0; q < 4; ++q)
        v[q] = __hip_atomic_load(&src[tid + TPB * q], __ATOMIC_RELAXED,
                                 __HIP_MEMORY_SCOPE_AGENT);
      for (int guard = 0;;) {
        const int miss = ((unsigned)(v[0] >> 32) != wanted) |
                         ((unsigned)(v[1] >> 32) != wanted) |
                         ((unsigned)(v[2] >> 32) != wanted) |
                         ((unsigned)(v[3] >> 32) != wanted);
        if (!__any(miss) || ++guard > GUARD_MAX) break;
        #pragma unroll
        for (int q = 0; q < 4; ++q)      // re-load only still-missing words
          if ((unsigned)(v[q] >> 32) != wanted)
            v[q] = __hip_atomic_load(&src[tid + TPB * q], __ATOMIC_RELAXED,
                                     __HIP_MEMORY_SCOPE_AGENT);
      }
      #pragma unroll
      for (int q = 0; q < 4; ++q) {
        hv[q] = __uint_as_float((unsigned)v[q]);
        hs[par][tid + TPB * q] = hv[q];
      }
    }
    __syncthreads();  // B1: hs[par] ready

    // ---- off-path: drain y_{t-2} (wys[par^1] written at step t-1) ----
    if (t >= 2 && wg == 0 && tid == 0)
      out[t - 2] = wys[par ^ 1][0] + wys[par ^ 1][1] + wys[par ^ 1][2] +
                   wys[par ^ 1][3] + wys[par ^ 1][4] + wys[par ^ 1][5] +
                   wys[par ^ 1][6] + wys[par ^ 1][7] + bout;

    // ---- z = W_hh @ h (per-lane partials over 32 columns) ----
    float acc[4] = {0.f, 0.f, 0.f, 0.f};
    #pragma unroll
    for (int j = 0; j < 8; ++j) {
      const float4 h4 = *(const float4*)&hs[par][j * 256 + lane * 4];
      #pragma unroll
      for (int g = 0; g < 4; ++g) {
        const float4 w = W[g * 8 + j];
        acc[g] = fmaf(w.x, h4.x, acc[g]);
        acc[g] = fmaf(w.y, h4.y, acc[g]);
        acc[g] = fmaf(w.z, h4.z, acc[g]);
        acc[g] = fmaf(w.w, h4.w, acc[g]);
      }
    }
    // ---- 16-shuffle reduction (verified prior rounds) ----
    const float a0 = acc[0] + __shfl_xor(acc[0], 32, 64);
    const float a1 = acc[1] + __shfl_xor(acc[1], 32, 64);
    const float a2 = acc[2] + __shfl_xor(acc[2], 32, 64);
    const float a3 = acc[3] + __shfl_xor(acc[3], 32, 64);
    const bool lohalf = (lane < 32);
    float s01 = lohalf ? a0 : a1;
    float s23 = lohalf ? a2 : a3;
    #pragma unroll
    for (int off = 16; off >= 1; off >>= 1) {
      s01 += __shfl_xor(s01, off, 64);
      s23 += __shfl_xor(s23, off, 64);
    }
    const float o01 = __shfl_xor(s01, 32, 64);
    const float o23 = __shfl_xor(s23, 32, 64);
    float z[4];
    z[0] = lohalf ? s01 : o01;
    z[1] = lohalf ? o01 : s01;
    z[2] = lohalf ? s23 : o23;
    z[3] = lohalf ? o23 : s23;

    const float xt = xs[t];
    #pragma unroll
    for (int g = 0; g < 4; ++g) z[g] = fmaf(xt, wx[g], z[g] + bb[g]);

    // ---- gates (lane-redundant, identical values) ----
    const float gi = sigmoidf_(z[0]), gf = sigmoidf_(z[1]);
    const float gg = tanh_(z[2]), go = sigmoidf_(z[3]);
    cc = gf * cc + gi * gg;
    hh = go * tanh_(cc);

    // ---- pack {stamp t+1, h_t} into LDS ----
    if (lane == 0)
      hpk[wave] = ((u64)(unsigned)(t + 1) << 32) | (u64)__float_as_uint(hh);
    __syncthreads();  // B2: hpk complete

    // ---- publish: wave 0 lanes 0..7 emit ONE 64B full-line store ----
    if (wave == 0 && lane < 8)
      __hip_atomic_store(&inbox[(size_t)(t & 1) * HDIM + wg * 8 + lane],
                         hpk[lane], __ATOMIC_RELAXED,
                         __HIP_MEMORY_SCOPE_AGENT);

    // ---- off-path: y_{t-1} partial from hv (h_{t-1}) ----
    float sy = 0.f;
    #pragma unroll
    for (int q = 0; q < 4; ++q) sy = fmaf(wo[q], hv[q], sy);
    #pragma unroll
    for (int off = 32; off >= 1; off >>= 1) sy += __shfl_xor(sy, off, 64);
    if (lane == 0) wys[par][wave] = sy;
  }

  // ---- epilogue ----
  __syncthreads();  // wys[1] (y partial for h_{SEQ-2}) complete
  if (wg == 0 && tid == 0)
    out[SEQ - 2] = wys[1][0] + wys[1][1] + wys[1][2] + wys[1][3] + wys[1][4] +
                   wys[1][5] + wys[1][6] + wys[1][7] + bout;

  // final h, c
  if (lane == 0) {
    out[SEQ + k] = hh;
    out[SEQ + HDIM + k] = cc;
  }

  if (wg == 0) {
    // y_{SEQ-1}: poll slot (SEQ-1)&1 == 1 for stamp SEQ
    const u64* src = inbox + (size_t)1 * HDIM;
    u64 v[4];
    #pragma unroll
    for (int q = 0; q < 4; ++q)
      v[q] = __hip_atomic_load(&src[tid + TPB * q], __ATOMIC_RELAXED,
                               __HIP_MEMORY_SCOPE_AGENT);
    for (int guard = 0;;) {
      const int miss = ((unsigned)(v[0] >> 32) != (unsigned)SEQ) |
                       ((unsigned)(v[1] >> 32) != (unsigned)SEQ) |
                       ((unsigned)(v[2] >> 32) != (unsigned)SEQ) |
                       ((unsigned)(v[3] >> 32) != (unsigned)SEQ);
      if (!__any(miss) || ++guard > GUARD_MAX) break;
      #pragma unroll
      for (int q = 0; q < 4; ++q)
        if ((unsigned)(v[q] >> 32) != (unsigned)SEQ)
          v[q] = __hip_atomic_load(&src[tid + TPB * q], __ATOMIC_RELAXED,
                                   __HIP_MEMORY_SCOPE_AGENT);
    }
    float sy = 0.f;
    #pragma unroll
    for (int q = 0; q < 4; ++q)
      sy = fmaf(wo[q], __uint_as_float((unsigned)v[q]), sy);
    #pragma unroll
    for (int off = 32; off >= 1; off >>= 1) sy += __shfl_xor(sy, off, 64);
    if (lane == 0) wys[0][wave] = sy;
    __syncthreads();
    if (tid == 0)
      out[SEQ - 1] = wys[0][0] + wys[0][1] + wys[0][2] + wys[0][3] +
                     wys[0][4] + wys[0][5] + wys[0][6] + wys[0][7] + bout;
  }
}

extern "C" void kernel_launch(void* const* d_in, const int* in_sizes, int n_in,
                              void* d_out, int out_size, void* d_ws, size_t ws_size,
                              hipStream_t stream) {
  const float* x     = (const float*)d_in[0];
  const float* w_ih  = (const float*)d_in[1];
  const float* w_hh  = (const float*)d_in[2];
  const float* b_ih  = (const float*)d_in[3];
  const float* b_hh  = (const float*)d_in[4];
  const float* w_out = (const float*)d_in[5];
  const float* b_out = (const float*)d_in[6];
  float* out = (float*)d_out;

  // ws layout: inbox[2][2048] u64 = 32 KB
  u64* inbox = (u64*)d_ws;

  lstm_init<<<16, 256, 0, stream>>>(inbox);
  lstm_persist<<<NWG, TPB, 0, stream>>>(x, w_ih, w_hh, b_ih, b_hh, w_out,
                                        b_out, out, inbox);
}